// Round 6
// baseline (422.615 us; speedup 1.0000x reference)
//
#include <hip/hip_runtime.h>

// SAGEConv: h[50000,64] f32, src/dst[800000] int32, W[128,64] f32, b[64] f32
// out = concat(h, mean_{in-edges}(h[src])) @ W + b
//
// R6: (a) gather table in bf16 (halves gather bytes, better L2 residency;
//     self-rows stay f32), (b) fine CSR eliminated -- fused kernel consumes
//     bucket-level (src,dst_local) packed pairs directly, accumulating into
//     LDS f32 via ds_add_f32, one block per 32-node bucket. 5 dispatches:
//     memset, prep(hist+bf16cvt), scank, bucket, fused.
// NOTE: pack (src<<5)|dst_local assumes n_nodes < 2^27.

#define IN_FEAT 64
#define KB_SHIFT 5                 // 32 nodes per bucket
#define BK (1 << KB_SHIFT)
#define KMAX 2048                  // supports n_nodes <= 65536

__device__ __forceinline__ unsigned short f2bf(float f) {
    unsigned u = __float_as_uint(f);
    return (unsigned short)((u + 0x7FFFu + ((u >> 16) & 1u)) >> 16);
}
__device__ __forceinline__ float bf2f(unsigned short s) {
    return __uint_as_float(((unsigned)s) << 16);
}

// ---- k1: bucket histogram (blocks [0,ehist)) + h->bf16 convert (rest) ------
__global__ __launch_bounds__(256) void sage_prep(
    const int* __restrict__ dst, const float* __restrict__ h,
    int* __restrict__ histc, unsigned short* __restrict__ hb,
    int n_edges, int n4, int ehist_tiles)
{
    __shared__ int cnt[KMAX];
    int t = (int)threadIdx.x;
    if ((int)blockIdx.x < ehist_tiles) {
        for (int k = t; k < KMAX; k += 256) cnt[k] = 0;
        __syncthreads();
        int base = blockIdx.x * 4096;
        #pragma unroll
        for (int i = 0; i < 16; ++i) {
            int e = base + t + i * 256;
            if (e < n_edges) atomicAdd(&cnt[dst[e] >> KB_SHIFT], 1);
        }
        __syncthreads();
        for (int k = t; k < KMAX; k += 256)
            if (cnt[k]) atomicAdd(&histc[k], cnt[k]);
    } else {
        int base = (blockIdx.x - ehist_tiles) * 4096;
        #pragma unroll
        for (int i = 0; i < 16; ++i) {
            int idx = base + t + i * 256;          // float4 index
            if (idx < n4) {
                float4 v = ((const float4*)h)[idx];
                ushort4 r;
                r.x = f2bf(v.x); r.y = f2bf(v.y);
                r.z = f2bf(v.z); r.w = f2bf(v.w);
                ((ushort4*)hb)[idx] = r;
            }
        }
    }
}

// ---- k2: scan bucket counts (single block, K <= 2048) ----------------------
__global__ __launch_bounds__(1024) void sage_scank(
    const int* __restrict__ histc, int* __restrict__ pbase,
    int* __restrict__ cursorA, int K)
{
    __shared__ int sh[1024];
    int t = (int)threadIdx.x;
    int running = 0;
    for (int base = 0; base < K; base += 1024) {
        int i = base + t;
        int v = (i < K) ? histc[i] : 0;
        sh[t] = v;
        __syncthreads();
        #pragma unroll
        for (int off = 1; off < 1024; off <<= 1) {
            int x = (t >= off) ? sh[t - off] : 0;
            __syncthreads();
            sh[t] += x;
            __syncthreads();
        }
        if (i < K) { int ex = running + sh[t] - v; pbase[i] = ex; cursorA[i] = ex; }
        int tot = sh[1023];
        __syncthreads();
        running += tot;
    }
    if (t == 0) pbase[K] = running;
}

// ---- k3: bucket the edges, packed u32 pairs (coalesced runs) ---------------
__global__ __launch_bounds__(256) void sage_bucket(
    const int* __restrict__ src, const int* __restrict__ dst,
    int* __restrict__ cursorA, unsigned* __restrict__ pairs, int n_edges)
{
    __shared__ int cnt[KMAX];
    __shared__ int base[KMAX];
    __shared__ int rnk[KMAX];
    int t = (int)threadIdx.x;
    for (int k = t; k < KMAX; k += 256) { cnt[k] = 0; rnk[k] = 0; }
    __syncthreads();

    int tb = blockIdx.x * 4096;
    int d[16], s[16], kb[16];
    #pragma unroll
    for (int i = 0; i < 16; ++i) {
        int e = tb + t + i * 256;
        kb[i] = -1;
        if (e < n_edges) {
            d[i] = dst[e]; s[i] = src[e];
            kb[i] = d[i] >> KB_SHIFT;
            atomicAdd(&cnt[kb[i]], 1);
        }
    }
    __syncthreads();
    for (int k = t; k < KMAX; k += 256) {
        int c = cnt[k];
        base[k] = c ? atomicAdd(&cursorA[k], c) : 0;
    }
    __syncthreads();
    #pragma unroll
    for (int i = 0; i < 16; ++i) {
        if (kb[i] >= 0) {
            int r = atomicAdd(&rnk[kb[i]], 1);
            pairs[base[kb[i]] + r] =
                ((unsigned)s[i] << KB_SHIFT) | (unsigned)(d[i] & (BK - 1));
        }
    }
}

// ---- k4: fused LDS-accumulate + MLP, one block per 32-node bucket ----------
// Edge stream: 16 lanes/edge x bf16x4 (8B), ds_add_f32 into acc[32][65]
// (pad 65: atomic bank = (dl+4q+c) mod 32 -> all 32 banks, 2-way = free).
// MLP: thread (nl=t>>4, q=t&15) -> node nl, columns 4q..4q+3; self row f32
// from global (broadcast), W rows ds_read_b128.
__global__ __launch_bounds__(512, 6) void sage_fused(
    const unsigned short* __restrict__ hb,
    const float* __restrict__ h,
    const unsigned* __restrict__ pairs,
    const int* __restrict__ pbase,
    const float* __restrict__ W,     // [128,64] row-major
    const float* __restrict__ bias,
    float* __restrict__ out,
    int n_nodes)
{
    __shared__ float Wsh[128][64];   // 32 KB
    __shared__ float acc[BK][65];    // 8.3 KB
    __shared__ float bsh[64];
    __shared__ int degsh[BK];
    // total ~41 KB -> 3 blocks/CU (24 waves)

    int t = (int)threadIdx.x;
    {   // stage W: 2048 float4s, 4 per thread
        float4* wd = (float4*)&Wsh[0][0];
        const float4* wsv = (const float4*)W;
        wd[t]        = wsv[t];
        wd[t + 512]  = wsv[t + 512];
        wd[t + 1024] = wsv[t + 1024];
        wd[t + 1536] = wsv[t + 1536];
    }
    if (t < 64) bsh[t] = bias[t];
    if (t < BK) degsh[t] = 0;
    for (int i = t; i < BK * 65; i += 512) ((float*)acc)[i] = 0.f;
    __syncthreads();

    const int b  = (int)blockIdx.x;
    const int pb = pbase[b], pe = pbase[b + 1];
    const int es = t >> 4;           // edge slot 0..31
    const int q  = t & 15;

    for (int e = pb + es; e < pe; e += 32) {
        unsigned p = pairs[e];
        int dl = (int)(p & (BK - 1));
        int s  = (int)(p >> KB_SHIFT);
        ushort4 hv = *(const ushort4*)(hb + ((size_t)s << 6) + q * 4);
        float4 v;
        v.x = bf2f(hv.x); v.y = bf2f(hv.y);
        v.z = bf2f(hv.z); v.w = bf2f(hv.w);
        atomicAdd(&acc[dl][q * 4 + 0], v.x);
        atomicAdd(&acc[dl][q * 4 + 1], v.y);
        atomicAdd(&acc[dl][q * 4 + 2], v.z);
        atomicAdd(&acc[dl][q * 4 + 3], v.w);
        if (q == 0) atomicAdd(&degsh[dl], 1);
    }
    __syncthreads();

    const int nl = t >> 4;           // local node 0..31
    const int n  = (b << KB_SHIFT) + nl;
    if (n < n_nodes) {
        int dg = degsh[nl];
        float inv = (dg > 0) ? (1.0f / (float)dg) : 0.f;
        const float* hrow = h + ((size_t)n << 6);
        float4 o = ((const float4*)bsh)[q];
        #pragma unroll
        for (int k4 = 0; k4 < 16; ++k4) {
            const float4 hq = *(const float4*)(hrow + k4 * 4);   // bcast x16
            #pragma unroll
            for (int c = 0; c < 4; ++c) {
                float hv = (&hq.x)[c];
                const float4 wv = *(const float4*)&Wsh[k4 * 4 + c][q * 4];
                o.x = fmaf(hv, wv.x, o.x);
                o.y = fmaf(hv, wv.y, o.y);
                o.z = fmaf(hv, wv.z, o.z);
                o.w = fmaf(hv, wv.w, o.w);
            }
        }
        #pragma unroll 16
        for (int k = 0; k < 64; ++k) {
            float hv = acc[nl][k] * inv;
            const float4 wv = *(const float4*)&Wsh[64 + k][q * 4];
            o.x = fmaf(hv, wv.x, o.x);
            o.y = fmaf(hv, wv.y, o.y);
            o.z = fmaf(hv, wv.z, o.z);
            o.w = fmaf(hv, wv.w, o.w);
        }
        *(float4*)(out + ((size_t)n << 6) + q * 4) = o;
    }
}

extern "C" void kernel_launch(void* const* d_in, const int* in_sizes, int n_in,
                              void* d_out, int out_size, void* d_ws, size_t ws_size,
                              hipStream_t stream) {
    const float* h   = (const float*)d_in[0];
    const int*   src = (const int*)d_in[1];
    const int*   dst = (const int*)d_in[2];
    const float* W   = (const float*)d_in[3];
    const float* b   = (const float*)d_in[4];
    float* out = (float*)d_out;

    const int n_nodes = in_sizes[0] / IN_FEAT;
    const int n_edges = in_sizes[1];
    const int K = (n_nodes + BK - 1) >> KB_SHIFT;      // 1563 for N=50000
    const int n4 = n_nodes * (IN_FEAT / 4);            // float4 count = 800000

    // ws layout: hb[N*64 ushort] | pairs[E u32] | histc[K] | pbase[K+1] | cursorA[K]
    unsigned short* hb = (unsigned short*)d_ws;
    unsigned* pairs = (unsigned*)(hb + (size_t)n_nodes * IN_FEAT);
    int* histc   = (int*)(pairs + n_edges);
    int* pbase   = histc + K;
    int* cursorA = pbase + (K + 1);

    hipMemsetAsync(histc, 0, (size_t)K * sizeof(int), stream);

    const int ehist_tiles = (n_edges + 4095) / 4096;   // 196
    const int conv_tiles  = (n4 + 4095) / 4096;        // 196
    sage_prep<<<ehist_tiles + conv_tiles, 256, 0, stream>>>(
        dst, h, histc, hb, n_edges, n4, ehist_tiles);
    sage_scank<<<1, 1024, 0, stream>>>(histc, pbase, cursorA, K);
    sage_bucket<<<ehist_tiles, 256, 0, stream>>>(src, dst, cursorA, pairs, n_edges);
    sage_fused<<<K, 512, 0, stream>>>(hb, h, pairs, pbase, W, b, out, n_nodes);
}

// Round 7
// 149.957 us; speedup vs baseline: 2.8182x; 2.8182x over previous
//
#include <hip/hip_runtime.h>

// SAGEConv: h[50000,64] f32, src/dst[800000] int32, W[128,64] f32, b[64] f32
// out = concat(h, mean_{in-edges}(h[src])) @ W + b
//
// R7 = R5 structure (CSR + read-side shfl reduction; R6's LDS-atomic
// accumulate regressed 153->423us: 51.2M ds-RMW serialize) plus:
//  - bf16 gather table (edge row read 256B->128B, working set 6.4MB ~ L2)
//  - packed u32 pairs (src<<7|dl): halves bucket write / csr read traffic
//  - h->bf16 conversion folded into the hist dispatch (still 5 dispatches)

#define IN_FEAT 64
#define KB_SHIFT 7            // 128 nodes per bucket
#define BK 128
#define KMAX 512              // supports n_nodes <= 65536

__device__ __forceinline__ unsigned short f2bf(float f) {
    unsigned u = __float_as_uint(f);
    return (unsigned short)((u + 0x7FFFu + ((u >> 16) & 1u)) >> 16);
}
__device__ __forceinline__ float bf2f(unsigned short s) {
    return __uint_as_float(((unsigned)s) << 16);
}

// ---- k1: bucket histogram (blocks [0,ehist)) + h->bf16 convert (rest) ------
__global__ __launch_bounds__(256) void sage_histk(
    const int* __restrict__ dst, const float* __restrict__ h,
    int* __restrict__ histc, unsigned short* __restrict__ hb,
    int n_edges, int n4, int ehist_tiles)
{
    __shared__ int cnt[KMAX];
    int t = (int)threadIdx.x;
    if ((int)blockIdx.x < ehist_tiles) {
        cnt[t] = 0; cnt[t + 256] = 0;
        __syncthreads();
        int base = blockIdx.x * 4096;
        #pragma unroll
        for (int i = 0; i < 16; ++i) {
            int e = base + t + i * 256;
            if (e < n_edges) atomicAdd(&cnt[dst[e] >> KB_SHIFT], 1);
        }
        __syncthreads();
        #pragma unroll
        for (int k = t; k < KMAX; k += 256)
            if (cnt[k]) atomicAdd(&histc[k], cnt[k]);
    } else {
        int base = (blockIdx.x - ehist_tiles) * 4096;
        #pragma unroll
        for (int i = 0; i < 16; ++i) {
            int idx = base + t + i * 256;          // float4 index
            if (idx < n4) {
                float4 v = ((const float4*)h)[idx];
                ushort4 r;
                r.x = f2bf(v.x); r.y = f2bf(v.y);
                r.z = f2bf(v.z); r.w = f2bf(v.w);
                ((ushort4*)hb)[idx] = r;
            }
        }
    }
}

// ---- k2: scan bucket counts (single block, K <= 512) -----------------------
__global__ __launch_bounds__(512) void sage_scank(
    const int* __restrict__ histc, int* __restrict__ pbase,
    int* __restrict__ cursorA, int K)
{
    __shared__ int sh[512];
    int t = (int)threadIdx.x;
    int v = (t < K) ? histc[t] : 0;
    sh[t] = v;
    __syncthreads();
    #pragma unroll
    for (int off = 1; off < 512; off <<= 1) {
        int x = (t >= off) ? sh[t - off] : 0;
        __syncthreads();
        sh[t] += x;
        __syncthreads();
    }
    int ex = sh[t] - v;
    if (t < K) { pbase[t] = ex; cursorA[t] = ex; }
    if (t == 511) pbase[K] = sh[511];
}

// ---- k3: bucket the edges, packed u32 (src<<7 | dst_local) -----------------
__global__ __launch_bounds__(256) void sage_bucket(
    const int* __restrict__ src, const int* __restrict__ dst,
    int* __restrict__ cursorA, unsigned* __restrict__ pairs, int n_edges)
{
    __shared__ int cnt[KMAX];
    __shared__ int base[KMAX];
    __shared__ int rnk[KMAX];
    int t = (int)threadIdx.x;
    #pragma unroll
    for (int k = t; k < KMAX; k += 256) { cnt[k] = 0; rnk[k] = 0; }
    __syncthreads();

    int tb = blockIdx.x * 4096;
    int d[16], s[16], kb[16];
    #pragma unroll
    for (int i = 0; i < 16; ++i) {
        int e = tb + t + i * 256;
        kb[i] = -1;
        if (e < n_edges) {
            d[i] = dst[e]; s[i] = src[e];
            kb[i] = d[i] >> KB_SHIFT;
            atomicAdd(&cnt[kb[i]], 1);
        }
    }
    __syncthreads();
    #pragma unroll
    for (int k = t; k < KMAX; k += 256) {
        int c = cnt[k];
        base[k] = c ? atomicAdd(&cursorA[k], c) : 0;
    }
    __syncthreads();
    #pragma unroll
    for (int i = 0; i < 16; ++i) {
        if (kb[i] >= 0) {
            int r = atomicAdd(&rnk[kb[i]], 1);
            pairs[base[kb[i]] + r] =
                ((unsigned)s[i] << KB_SHIFT) | (unsigned)(d[i] & (BK - 1));
        }
    }
}

// ---- k4: per-bucket fine CSR (LDS cursors, window-local scatter) -----------
__global__ __launch_bounds__(256) void sage_csr(
    const unsigned* __restrict__ pairs, const int* __restrict__ pbase,
    int* __restrict__ row_start, int* __restrict__ csr_src,
    int n_nodes, int K)
{
    __shared__ int cnt[BK];
    __shared__ int sh[BK];
    __shared__ int cur[BK];
    int b = blockIdx.x;
    int t = (int)threadIdx.x;
    int nlo = b << KB_SHIFT;
    int nn  = min(BK, n_nodes - nlo);
    int pb = pbase[b], pe = pbase[b + 1];

    if (t < BK) cnt[t] = 0;
    __syncthreads();
    for (int e = pb + t; e < pe; e += 256)
        atomicAdd(&cnt[pairs[e] & (BK - 1)], 1);
    __syncthreads();
    int v = (t < BK) ? cnt[t] : 0;
    if (t < BK) sh[t] = v;
    __syncthreads();
    #pragma unroll
    for (int off = 1; off < BK; off <<= 1) {
        int x = (t < BK && t >= off) ? sh[t - off] : 0;
        __syncthreads();
        if (t < BK) sh[t] += x;
        __syncthreads();
    }
    if (t < nn) {
        int abs0 = pb + sh[t] - v;
        row_start[nlo + t] = abs0;
        cur[t] = abs0;
    }
    if (b == K - 1 && t == 0) row_start[n_nodes] = pe;
    __syncthreads();
    for (int e = pb + t; e < pe; e += 256) {
        unsigned p = pairs[e];
        int pos = atomicAdd(&cur[p & (BK - 1)], 1);
        csr_src[pos] = (int)(p >> KB_SHIFT);
    }
}

// ---- k5: fused gather-mean (bf16) + [h,h_N]@W + b --------------------------
// Block = 1024 (16 waves); wave w owns nodes 4w..4w+3 both phases ->
// wave-private LDS, no in-loop barriers. Gather: 16 lanes/edge x ushort4
// (128B/edge), 2x unroll, __shfl_xor(16,32) reduce. MLP: lane (sub,q) ->
// node nbase+sub, cols 4q..4q+3; self row f32 global, W rows ds_read_b128.
__global__ __launch_bounds__(1024, 8) void sage_fused(
    const unsigned short* __restrict__ hb,
    const float* __restrict__ h,
    const int* __restrict__ row_start,
    const int* __restrict__ csr_src,
    const float* __restrict__ W,     // [128,64] row-major
    const float* __restrict__ bias,
    float* __restrict__ out,
    int n_nodes)
{
    __shared__ float Wsh[128][64];   // 32 KB
    __shared__ float bsh[64];
    __shared__ float hn[64][68];     // pad 68: 16B-aligned + bank-spread

    const int t = (int)threadIdx.x;
    {   // stage W: 2048 float4s, 2 per thread
        float4* wd = (float4*)&Wsh[0][0];
        const float4* wsv = (const float4*)W;
        wd[t]        = wsv[t];
        wd[t + 1024] = wsv[t + 1024];
    }
    if (t < 64) bsh[t] = bias[t];
    __syncthreads();

    const int w    = t >> 6;
    const int lane = t & 63;
    const int sub  = lane >> 4;
    const int q    = lane & 15;

    const int ngroups = (n_nodes + 63) >> 6;
    for (int g = blockIdx.x; g < ngroups; g += gridDim.x) {
        const int nbase = g * 64 + w * 4;

        #pragma unroll
        for (int i = 0; i < 4; ++i) {
            int n = nbase + i;
            if (n >= n_nodes) break;             // wave-uniform
            int slot = w * 4 + i;
            int beg = row_start[n], end = row_start[n + 1];
            float4 acc = make_float4(0.f, 0.f, 0.f, 0.f);
            int e = beg + sub;
            for (; e + 4 < end; e += 8) {
                int s0 = csr_src[e], s1 = csr_src[e + 4];
                const ushort4 u0 = *(const ushort4*)(hb + ((size_t)s0 << 6) + q * 4);
                const ushort4 u1 = *(const ushort4*)(hb + ((size_t)s1 << 6) + q * 4);
                acc.x += bf2f(u0.x) + bf2f(u1.x);
                acc.y += bf2f(u0.y) + bf2f(u1.y);
                acc.z += bf2f(u0.z) + bf2f(u1.z);
                acc.w += bf2f(u0.w) + bf2f(u1.w);
            }
            if (e < end) {
                int s0 = csr_src[e];
                const ushort4 u0 = *(const ushort4*)(hb + ((size_t)s0 << 6) + q * 4);
                acc.x += bf2f(u0.x); acc.y += bf2f(u0.y);
                acc.z += bf2f(u0.z); acc.w += bf2f(u0.w);
            }
            #pragma unroll
            for (int m = 16; m < 64; m <<= 1) {
                acc.x += __shfl_xor(acc.x, m);
                acc.y += __shfl_xor(acc.y, m);
                acc.z += __shfl_xor(acc.z, m);
                acc.w += __shfl_xor(acc.w, m);
            }
            int deg = end - beg;
            float inv = (deg > 0) ? (1.0f / (float)deg) : 0.f;
            if (sub == 0)
                *(float4*)&hn[slot][q * 4] =
                    make_float4(acc.x * inv, acc.y * inv, acc.z * inv, acc.w * inv);
        }
        __builtin_amdgcn_wave_barrier();

        {
            int n2 = nbase + sub;
            if (n2 < n_nodes) {
                int slot = w * 4 + sub;
                const float* hrow = h + ((size_t)n2 << 6);
                float4 acc = ((const float4*)bsh)[q];
                #pragma unroll
                for (int k4 = 0; k4 < 16; ++k4) {
                    const float4 hq = *(const float4*)(hrow + k4 * 4);
                    #pragma unroll
                    for (int c = 0; c < 4; ++c) {
                        float hv = (&hq.x)[c];
                        const float4 wv = *(const float4*)&Wsh[k4 * 4 + c][q * 4];
                        acc.x = fmaf(hv, wv.x, acc.x);
                        acc.y = fmaf(hv, wv.y, acc.y);
                        acc.z = fmaf(hv, wv.z, acc.z);
                        acc.w = fmaf(hv, wv.w, acc.w);
                    }
                }
                #pragma unroll 16
                for (int k = 0; k < 64; ++k) {
                    float hv = hn[slot][k];
                    const float4 wv = *(const float4*)&Wsh[64 + k][q * 4];
                    acc.x = fmaf(hv, wv.x, acc.x);
                    acc.y = fmaf(hv, wv.y, acc.y);
                    acc.z = fmaf(hv, wv.z, acc.z);
                    acc.w = fmaf(hv, wv.w, acc.w);
                }
                *(float4*)(out + ((size_t)n2 << 6) + q * 4) = acc;
            }
        }
        __builtin_amdgcn_wave_barrier();
    }
}

extern "C" void kernel_launch(void* const* d_in, const int* in_sizes, int n_in,
                              void* d_out, int out_size, void* d_ws, size_t ws_size,
                              hipStream_t stream) {
    const float* h   = (const float*)d_in[0];
    const int*   src = (const int*)d_in[1];
    const int*   dst = (const int*)d_in[2];
    const float* W   = (const float*)d_in[3];
    const float* b   = (const float*)d_in[4];
    float* out = (float*)d_out;

    const int n_nodes = in_sizes[0] / IN_FEAT;
    const int n_edges = in_sizes[1];
    const int K = (n_nodes + BK - 1) >> KB_SHIFT;      // 391
    const int n4 = n_nodes * (IN_FEAT / 4);            // 800000 float4s

    // ws: hb[N*64 ushort] | pairs[E u32] | csr_src[E] | row_start[N+1] |
    //     histc[K] | pbase[K+1] | cursorA[K]
    unsigned short* hb = (unsigned short*)d_ws;
    unsigned* pairs    = (unsigned*)(hb + (size_t)n_nodes * IN_FEAT);
    int* csr_src       = (int*)(pairs + n_edges);
    int* row_start     = csr_src + n_edges;
    int* histc         = row_start + (n_nodes + 1);
    int* pbase         = histc + K;
    int* cursorA       = pbase + (K + 1);

    hipMemsetAsync(histc, 0, (size_t)K * sizeof(int), stream);

    const int ehist_tiles = (n_edges + 4095) / 4096;   // 196
    const int conv_tiles  = (n4 + 4095) / 4096;        // 196
    sage_histk<<<ehist_tiles + conv_tiles, 256, 0, stream>>>(
        dst, h, histc, hb, n_edges, n4, ehist_tiles);
    sage_scank<<<1, 512, 0, stream>>>(histc, pbase, cursorA, K);
    sage_bucket<<<ehist_tiles, 256, 0, stream>>>(src, dst, cursorA, pairs, n_edges);
    sage_csr<<<K, 256, 0, stream>>>(pairs, pbase, row_start, csr_src, n_nodes, K);
    {
        int ngroups = (n_nodes + 63) / 64;             // 782
        int grid = ngroups < 512 ? ngroups : 512;      // 2 blocks/CU
        sage_fused<<<grid, 1024, 0, stream>>>(hb, h, row_start, csr_src,
                                              W, b, out, n_nodes);
    }
}